// Round 7
// baseline (406.119 us; speedup 1.0000x reference)
//
#include <hip/hip_runtime.h>

#define IMG_W 512
#define IMG_H 512
#define TILE 88      // output tile per block
#define HALO 20      // >= 19 dilation steps of halo
#define NSUP 9       // super-steps (2 dilations each) -> steps 1..18; +1 final step
#define RH 8
#define RW 8
#define REG 128      // region = 128x128, threads 16x16, 8x8 px/thread in regs

__device__ __forceinline__ float max3f(float a, float b, float c) {
    return fmaxf(fmaxf(a, b), c);   // -> v_max3_f32
}

// DPP lane shifts within 16-lane rows (tx = lane%16). bound_ctrl=1: 0-fill at
// the 16-lane boundary = region cols 0/127 (halo, tolerated by budget).
__device__ __forceinline__ float dpp_shr1(float v) { // receive from lane-1
    int i = __builtin_bit_cast(int, v);
    i = __builtin_amdgcn_update_dpp(0, i, 0x111, 0xf, 0xf, true); // row_shr:1
    return __builtin_bit_cast(float, i);
}
__device__ __forceinline__ float dpp_shl1(float v) { // receive from lane+1
    int i = __builtin_bit_cast(int, v);
    i = __builtin_amdgcn_update_dpp(0, i, 0x101, 0xf, 0xf, true); // row_shl:1
    return __builtin_bit_cast(float, i);
}
// Pull value from an arbitrary lane (byte addr = srcLane*4, wraps mod 64).
__device__ __forceinline__ float bperm(int byteAddr, float v) {
    int i = __builtin_amdgcn_ds_bpermute(byteAddr, __builtin_bit_cast(int, v));
    return __builtin_bit_cast(float, i);
}

// Horizontal 3-max. NO masking: invariant is A==0 at out-of-image cells at the
// start of each step; consumers mask the dilated value once.
__device__ __forceinline__ void hrow(const float (&Ar)[RW], float (&h)[RW]) {
    float hl = dpp_shr1(Ar[RW - 1]);
    float hr = dpp_shl1(Ar[0]);
    h[0] = max3f(hl, Ar[0], Ar[1]);
    #pragma unroll
    for (int c = 1; c < RW - 1; ++c) h[c] = max3f(Ar[c - 1], Ar[c], Ar[c + 1]);
    h[RW - 1] = max3f(Ar[RW - 2], Ar[RW - 1], hr);
}

// Masked D row from 3 h rows.
template<bool XM, bool YM>
__device__ __forceinline__ void drow(const float (&ha)[RW], const float (&hb)[RW],
                                     const float (&hc)[RW], float (&d)[RW],
                                     const float (&colm)[RW], float rm, bool needR) {
    #pragma unroll
    for (int c = 0; c < RW; ++c) d[c] = max3f(ha[c], hb[c], hc[c]);
    if (XM) {
        #pragma unroll
        for (int c = 0; c < RW; ++c) d[c] *= colm[c];
    }
    if (YM) {
        if (needR) {
            #pragma unroll
            for (int c = 0; c < RW; ++c) d[c] *= rm;
        }
    }
}

// Two fused dilation steps from one exchange of raw A halo rows (-2,-1,8,9).
// h1 over rows -2..9, D1 over rows -1..8 (acc += for 0..7), h2 on the fly,
// D2 over rows 0..7 (A overwritten in place, acc += ).
template<bool XM, bool YM>
__device__ __forceinline__ void dil2(float (&A)[RH][RW], float (&acc)[RH][RW],
        const float (&Am2)[RW], const float (&Am1)[RW],
        const float (&Ap8)[RW], const float (&Ap9)[RW],
        const float (&colm)[RW], const float (&rowm)[RH],
        float rmm1, float rm8, bool needR)
{
    float h1[3][RW], h2[3][RW];
    hrow(A[0], h1[0]);      // row 0 early (independent of halo reads)
    hrow(Am2, h1[1]);       // row -2 -> slot 1
    hrow(Am1, h1[2]);       // row -1 -> slot 2
    #pragma unroll
    for (int i = 0; i <= 9; ++i) {
        if (i >= 1) {       // h1 row i -> slot i%3 (row 0 precomputed)
            if (i <= 7)      hrow(A[i], h1[i % 3]);
            else if (i == 8) hrow(Ap8, h1[2]);   // 8%3
            else             hrow(Ap9, h1[0]);   // 9%3
        }
        {   // D1 row rr = i-1 from h1 rows rr-1, rr, rr+1
            const int rr = i - 1;
            const int sa = (rr + 2) % 3;         // slot of row rr-1
            const int sb = (rr + 3) % 3;         // slot of row rr
            const int sc = i % 3;                // slot of row rr+1
            float D1[RW];
            const float rmv = YM ? ((rr == -1) ? rmm1
                                  : ((rr == 8) ? rm8
                                  : rowm[(rr >= 0 && rr <= 7) ? rr : 0])) : 1.f;
            drow<XM, YM>(h1[sa], h1[sb], h1[sc], D1, colm, rmv, needR);
            if (rr >= 0 && rr <= 7) {
                #pragma unroll
                for (int c = 0; c < RW; ++c) acc[rr][c] += D1[c];
            }
            hrow(D1, h2[sb]);                    // h2 row rr -> slot rr%3
        }
        if (i >= 2) {       // D2 row rd = i-2 from h2 rows rd-1, rd, rd+1
            const int rd = i - 2;
            const int sa = (rd + 2) % 3, sb = rd % 3, sc = (rd + 1) % 3;
            float D2[RW];
            drow<XM, YM>(h2[sa], h2[sb], h2[sc], D2, colm, YM ? rowm[rd] : 1.f, needR);
            #pragma unroll
            for (int c = 0; c < RW; ++c) { A[rd][c] = D2[c]; acc[rd][c] += D2[c]; }
        }
    }
}

// Single dilation step from exchanged raw rows -1, 8.
template<bool XM, bool YM>
__device__ __forceinline__ void dil1(float (&A)[RH][RW], float (&acc)[RH][RW],
        const float (&Am1)[RW], const float (&Ap8)[RW],
        const float (&colm)[RW], const float (&rowm)[RH], bool needR)
{
    float h[3][RW];
    hrow(A[0], h[0]);
    hrow(Am1, h[2]);        // row -1 -> slot 2
    #pragma unroll
    for (int i = 1; i <= 8; ++i) {
        if (i <= 7) hrow(A[i], h[i % 3]);
        else        hrow(Ap8, h[2]);             // row 8 -> slot 8%3
        const int rd = i - 1;
        const int sa = (rd + 2) % 3, sb = rd % 3, sc = i % 3;
        float D[RW];
        drow<XM, YM>(h[sa], h[sb], h[sc], D, colm, YM ? rowm[rd] : 1.f, needR);
        #pragma unroll
        for (int c = 0; c < RW; ++c) { A[rd][c] = D[c]; acc[rd][c] += D[c]; }
    }
}

template<bool XM, bool YM>
__device__ __forceinline__ void body(const float* __restrict__ xc, float* __restrict__ oc,
                                     int gx0, int gy0, int tx, int ty, int lane,
                                     float4 (*botR)[4][16][2][2], float4 (*topR)[4][16][2][2]) {
    const int rx = tx * RW;
    const int ry = ty * RH;
    const int gx = gx0 + rx;
    const int gy = gy0 + ry;

    float A[RH][RW];    // current image
    float acc[RH][RW];  // k=0 term + sum of D_k
    float colm[RW], rowm[RH];
    float rmm1 = 1.f, rm8 = 1.f;
    bool needR = false, needRE = false;

    if (XM) {
        #pragma unroll
        for (int c = 0; c < RW; ++c) {
            int xx = gx + c;
            colm[c] = (xx >= 0 && xx < IMG_W) ? 1.f : 0.f;
        }
    }
    if (YM) {
        #pragma unroll
        for (int r = 0; r < RH; ++r) {
            int yy = gy + r;
            rowm[r] = (yy >= 0 && yy < IMG_H) ? 1.f : 0.f;
        }
        rmm1 = (gy - 1 >= 0 && gy - 1 < IMG_H) ? 1.f : 0.f;
        rm8  = (gy + 8 >= 0 && gy + 8 < IMG_H) ? 1.f : 0.f;
        needR  = (gy < 0) || (gy + RH > IMG_H);
        needRE = (gy <= 0) || (gy + RH + 1 > IMG_H);
    }

    if (XM || YM) {
        const bool fullin = (gx >= 0) && (gx + RW <= IMG_W) && (gy >= 0) && (gy + RH <= IMG_H);
        if (fullin) {
            #pragma unroll
            for (int r = 0; r < RH; ++r) {
                const float4* rp = (const float4*)(xc + (size_t)(gy + r) * IMG_W + gx);
                float4 v0 = rp[0], v1 = rp[1];
                A[r][0] = v0.x; A[r][1] = v0.y; A[r][2] = v0.z; A[r][3] = v0.w;
                A[r][4] = v1.x; A[r][5] = v1.y; A[r][6] = v1.z; A[r][7] = v1.w;
            }
        } else {
            #pragma unroll
            for (int r = 0; r < RH; ++r) {
                const int yr = gy + r;
                const int yy = min(max(yr, 0), IMG_H - 1);
                float rmv = (yr >= 0 && yr < IMG_H) ? 1.f : 0.f;
                const float* rp = xc + (size_t)yy * IMG_W;
                #pragma unroll
                for (int c = 0; c < RW; ++c) {
                    const int xr = gx + c;
                    const int xx = min(max(xr, 0), IMG_W - 1);
                    float m = rmv;
                    if (XM) m *= colm[c];
                    A[r][c] = rp[xx] * m;
                }
            }
        }
    } else {
        #pragma unroll
        for (int r = 0; r < RH; ++r) {
            const float4* rp = (const float4*)(xc + (size_t)(gy + r) * IMG_W + gx);
            float4 v0 = rp[0], v1 = rp[1];
            A[r][0] = v0.x; A[r][1] = v0.y; A[r][2] = v0.z; A[r][3] = v0.w;
            A[r][4] = v1.x; A[r][5] = v1.y; A[r][6] = v1.z; A[r][7] = v1.w;
        }
    }
    #pragma unroll
    for (int r = 0; r < RH; ++r) {
        #pragma unroll
        for (int c = 0; c < RW; ++c) acc[r][c] = A[r][c];
    }

    // Vertical neighbors: lane -/+16 within the wave for 3 of 4 chunk-row
    // boundaries; wrap garbage lands only in region edge rows (halo budget).
    const int upA = ((lane - 16) & 63) << 2;
    const int dnA = ((lane + 16) & 63) << 2;
    const int gq = ty >> 2;   // slab (wave) id 0..3
    const int tw = ty & 3;    // chunk-row within slab

    #pragma unroll 1
    for (int t = 0; t < NSUP; ++t) {
        float Am2[RW], Am1[RW], Ap8[RW], Ap9[RW];
        #pragma unroll
        for (int c = 0; c < RW; ++c) {
            Am2[c] = bperm(upA, A[6][c]);
            Am1[c] = bperm(upA, A[7][c]);
            Ap8[c] = bperm(dnA, A[0][c]);
            Ap9[c] = bperm(dnA, A[1][c]);
        }
        const int buf = t & 1;
        if (tw == 3) {
            botR[buf][gq][tx][0][0] = make_float4(A[6][0], A[6][1], A[6][2], A[6][3]);
            botR[buf][gq][tx][0][1] = make_float4(A[6][4], A[6][5], A[6][6], A[6][7]);
            botR[buf][gq][tx][1][0] = make_float4(A[7][0], A[7][1], A[7][2], A[7][3]);
            botR[buf][gq][tx][1][1] = make_float4(A[7][4], A[7][5], A[7][6], A[7][7]);
        } else if (tw == 0) {
            topR[buf][gq][tx][0][0] = make_float4(A[0][0], A[0][1], A[0][2], A[0][3]);
            topR[buf][gq][tx][0][1] = make_float4(A[0][4], A[0][5], A[0][6], A[0][7]);
            topR[buf][gq][tx][1][0] = make_float4(A[1][0], A[1][1], A[1][2], A[1][3]);
            topR[buf][gq][tx][1][1] = make_float4(A[1][4], A[1][5], A[1][6], A[1][7]);
        }
        __syncthreads();
        if (tw == 0) {
            if (gq > 0) {
                float4 a0 = botR[buf][gq - 1][tx][0][0], a1 = botR[buf][gq - 1][tx][0][1];
                float4 b0 = botR[buf][gq - 1][tx][1][0], b1 = botR[buf][gq - 1][tx][1][1];
                Am2[0] = a0.x; Am2[1] = a0.y; Am2[2] = a0.z; Am2[3] = a0.w;
                Am2[4] = a1.x; Am2[5] = a1.y; Am2[6] = a1.z; Am2[7] = a1.w;
                Am1[0] = b0.x; Am1[1] = b0.y; Am1[2] = b0.z; Am1[3] = b0.w;
                Am1[4] = b1.x; Am1[5] = b1.y; Am1[6] = b1.z; Am1[7] = b1.w;
            }
        } else if (tw == 3) {
            if (gq < 3) {
                float4 a0 = topR[buf][gq + 1][tx][0][0], a1 = topR[buf][gq + 1][tx][0][1];
                float4 b0 = topR[buf][gq + 1][tx][1][0], b1 = topR[buf][gq + 1][tx][1][1];
                Ap8[0] = a0.x; Ap8[1] = a0.y; Ap8[2] = a0.z; Ap8[3] = a0.w;
                Ap8[4] = a1.x; Ap8[5] = a1.y; Ap8[6] = a1.z; Ap8[7] = a1.w;
                Ap9[0] = b0.x; Ap9[1] = b0.y; Ap9[2] = b0.z; Ap9[3] = b0.w;
                Ap9[4] = b1.x; Ap9[5] = b1.y; Ap9[6] = b1.z; Ap9[7] = b1.w;
            }
        }
        dil2<XM, YM>(A, acc, Am2, Am1, Ap8, Ap9, colm, rowm, rmm1, rm8, needRE);
    }

    // Final 19th dilation: single step, one more exchange (rows -1, 8 only).
    {
        float Am1[RW], Ap8[RW];
        #pragma unroll
        for (int c = 0; c < RW; ++c) {
            Am1[c] = bperm(upA, A[7][c]);
            Ap8[c] = bperm(dnA, A[0][c]);
        }
        const int buf = NSUP & 1;   // 1: last written at t=7, safe
        if (tw == 3) {
            botR[buf][gq][tx][1][0] = make_float4(A[7][0], A[7][1], A[7][2], A[7][3]);
            botR[buf][gq][tx][1][1] = make_float4(A[7][4], A[7][5], A[7][6], A[7][7]);
        } else if (tw == 0) {
            topR[buf][gq][tx][0][0] = make_float4(A[0][0], A[0][1], A[0][2], A[0][3]);
            topR[buf][gq][tx][0][1] = make_float4(A[0][4], A[0][5], A[0][6], A[0][7]);
        }
        __syncthreads();
        if (tw == 0) {
            if (gq > 0) {
                float4 b0 = botR[buf][gq - 1][tx][1][0], b1 = botR[buf][gq - 1][tx][1][1];
                Am1[0] = b0.x; Am1[1] = b0.y; Am1[2] = b0.z; Am1[3] = b0.w;
                Am1[4] = b1.x; Am1[5] = b1.y; Am1[6] = b1.z; Am1[7] = b1.w;
            }
        } else if (tw == 3) {
            if (gq < 3) {
                float4 a0 = topR[buf][gq + 1][tx][0][0], a1 = topR[buf][gq + 1][tx][0][1];
                Ap8[0] = a0.x; Ap8[1] = a0.y; Ap8[2] = a0.z; Ap8[3] = a0.w;
                Ap8[4] = a1.x; Ap8[5] = a1.y; Ap8[6] = a1.z; Ap8[7] = a1.w;
            }
        }
        dil1<XM, YM>(A, acc, Am1, Ap8, colm, rowm, needR);
    }

    // Epilogue: store central TILE x TILE (region coords [HALO, HALO+TILE))
    if (XM || YM) {
        #pragma unroll
        for (int r = 0; r < RH; ++r) {
            const int rr = ry + r;
            const int yy = gy0 + rr;
            if (rr >= HALO && rr < HALO + TILE && yy < IMG_H) {
                #pragma unroll
                for (int c = 0; c < RW; ++c) {
                    const int cc = rx + c;
                    const int xx = gx0 + cc;
                    if (cc >= HALO && cc < HALO + TILE && xx < IMG_W)
                        oc[(size_t)yy * IMG_W + xx] = 0.05f * acc[r][c];
                }
            }
        }
    } else {
        #pragma unroll
        for (int r = 0; r < RH; ++r) {
            const int rr = ry + r;
            if (rr < HALO || rr >= HALO + TILE) continue;
            const int yy = gy0 + rr;
            float* rowp = oc + (size_t)yy * IMG_W + gx;
            if (tx >= 3 && tx <= 12) {
                ((float4*)rowp)[0] = make_float4(0.05f * acc[r][0], 0.05f * acc[r][1],
                                                 0.05f * acc[r][2], 0.05f * acc[r][3]);
                ((float4*)rowp)[1] = make_float4(0.05f * acc[r][4], 0.05f * acc[r][5],
                                                 0.05f * acc[r][6], 0.05f * acc[r][7]);
            } else if (tx == 2) {        // cols 16..23, valid 20..23 -> c=4..7
                ((float4*)rowp)[1] = make_float4(0.05f * acc[r][4], 0.05f * acc[r][5],
                                                 0.05f * acc[r][6], 0.05f * acc[r][7]);
            } else if (tx == 13) {       // cols 104..111, valid 104..107 -> c=0..3
                ((float4*)rowp)[0] = make_float4(0.05f * acc[r][0], 0.05f * acc[r][1],
                                                 0.05f * acc[r][2], 0.05f * acc[r][3]);
            }
        }
    }
}

__global__ __launch_bounds__(256, 2)
void blur_outwards_kernel(const float* __restrict__ x, float* __restrict__ out) {
    // Cross-slab halo rows: [buf][slab][tx][2 rows][2 float4] = 8 KB each.
    __shared__ float4 botR[2][4][16][2][2];
    __shared__ float4 topR[2][4][16][2][2];

    const int tid = threadIdx.x;
    const int tx = tid & 15;
    const int ty = tid >> 4;
    const int lane = tid & 63;

    const int ch  = blockIdx.z;                       // 0..95
    const int gx0 = (int)blockIdx.x * TILE - HALO;
    const int gy0 = (int)blockIdx.y * TILE - HALO;

    const float* __restrict__ xc = x + (size_t)ch * (IMG_W * IMG_H);
    float* __restrict__ oc = out + (size_t)ch * (IMG_W * IMG_H);

    const bool xe = (gx0 < 0) || (gx0 + REG > IMG_W);
    const bool ye = (gy0 < 0) || (gy0 + REG > IMG_H);
    if (!xe && !ye)      body<false, false>(xc, oc, gx0, gy0, tx, ty, lane, botR, topR);
    else if (xe && !ye)  body<true,  false>(xc, oc, gx0, gy0, tx, ty, lane, botR, topR);
    else if (!xe && ye)  body<false, true >(xc, oc, gx0, gy0, tx, ty, lane, botR, topR);
    else                 body<true,  true >(xc, oc, gx0, gy0, tx, ty, lane, botR, topR);
}

extern "C" void kernel_launch(void* const* d_in, const int* in_sizes, int n_in,
                              void* d_out, int out_size, void* d_ws, size_t ws_size,
                              hipStream_t stream) {
    const float* x = (const float*)d_in[0];
    float* out = (float*)d_out;
    dim3 grid((IMG_W + TILE - 1) / TILE,   // 6
              (IMG_H + TILE - 1) / TILE,   // 6
              96);                          // 32 batch * 3 channels
    blur_outwards_kernel<<<grid, 256, 0, stream>>>(x, out);
}

// Round 8
// 302.639 us; speedup vs baseline: 1.3419x; 1.3419x over previous
//
#include <hip/hip_runtime.h>

#define IMG_W 512
#define IMG_H 512
#define TILE 88      // output tile per block
#define HALO 20      // >= 19 dilation steps of halo
#define NSTEP 19     // dilations accumulated (k=1..19; k=0 term is x itself)
#define RH 4         // chunk rows per thread (halved: state = 64 floats)
#define RW 8
#define REG 128      // region = 128x128; threads 16x32, 4x8 px/thread

__device__ __forceinline__ float max3f(float a, float b, float c) {
    return fmaxf(fmaxf(a, b), c);   // -> v_max3_f32
}

// DPP lane shifts within 16-lane rows (tx = lane%16). bound_ctrl=1: 0-fill at
// the 16-lane boundary = region cols 0/127 (halo, garbage-tolerant).
__device__ __forceinline__ float dpp_shr1(float v) { // receive from lane-1
    int i = __builtin_bit_cast(int, v);
    i = __builtin_amdgcn_update_dpp(0, i, 0x111, 0xf, 0xf, true); // row_shr:1
    return __builtin_bit_cast(float, i);
}
__device__ __forceinline__ float dpp_shl1(float v) { // receive from lane+1
    int i = __builtin_bit_cast(int, v);
    i = __builtin_amdgcn_update_dpp(0, i, 0x101, 0xf, 0xf, true); // row_shl:1
    return __builtin_bit_cast(float, i);
}

// Horizontal 3-max. NO masking: invariant is A==0 at out-of-image cells at the
// start of each step; consumers mask the dilated value once.
__device__ __forceinline__ void hrow(const float (&Ar)[RW], float (&h)[RW]) {
    float hl = dpp_shr1(Ar[RW - 1]);
    float hr = dpp_shl1(Ar[0]);
    h[0] = max3f(hl, Ar[0], Ar[1]);
    #pragma unroll
    for (int c = 1; c < RW - 1; ++c) h[c] = max3f(Ar[c - 1], Ar[c], Ar[c + 1]);
    h[RW - 1] = max3f(Ar[RW - 2], Ar[RW - 1], hr);
}

// One output row: D = max3(h[r-1], h[r], h[r+1]); mask ONCE on the result.
template<bool XM, bool YM>
__device__ __forceinline__ void rowop(const float (&hm1)[RW], const float (&hc)[RW],
                                      const float (&hn)[RW], float (&Ar)[RW],
                                      float (&accr)[RW], const float (&colm)[RW],
                                      float rm, bool needR) {
    float v[RW];
    #pragma unroll
    for (int c = 0; c < RW; ++c) v[c] = max3f(hm1[c], hc[c], hn[c]);
    if (XM) {
        #pragma unroll
        for (int c = 0; c < RW; ++c) v[c] *= colm[c];
    }
    if (YM) {
        if (needR) {
            #pragma unroll
            for (int c = 0; c < RW; ++c) v[c] *= rm;
        }
    }
    #pragma unroll
    for (int c = 0; c < RW; ++c) { Ar[c] = v[c]; accr[c] += v[c]; }
}

template<bool XM, bool YM>
__device__ __forceinline__ void body(const float* __restrict__ xc, float* __restrict__ oc,
                                     int gx0, int gy0, int tx, int ty,
                                     float4 (*topH4)[2][32][16], float4 (*botH4)[2][32][16]) {
    const int rx = tx * RW;      // chunk origin in region coords
    const int ry = ty * RH;
    const int gx = gx0 + rx;     // chunk origin in global coords
    const int gy = gy0 + ry;

    float A[RH][RW];    // current image (32 floats)
    float acc[RH][RW];  // sum of D_k   (32 floats)
    float colm[RW], rowm[RH];
    bool needR = false;

    if (XM) {
        #pragma unroll
        for (int c = 0; c < RW; ++c) {
            int xx = gx + c;
            colm[c] = (xx >= 0 && xx < IMG_W) ? 1.f : 0.f;
        }
    }
    if (YM) {
        #pragma unroll
        for (int r = 0; r < RH; ++r) {
            int yy = gy + r;
            rowm[r] = (yy >= 0 && yy < IMG_H) ? 1.f : 0.f;
        }
        needR = (gy < 0) || (gy + RH > IMG_H);
    }

    if (XM || YM) {
        const bool fullin = (gx >= 0) && (gx + RW <= IMG_W) && (gy >= 0) && (gy + RH <= IMG_H);
        if (fullin) {
            #pragma unroll
            for (int r = 0; r < RH; ++r) {
                const float4* rp = (const float4*)(xc + (size_t)(gy + r) * IMG_W + gx);
                float4 v0 = rp[0], v1 = rp[1];
                A[r][0] = v0.x; A[r][1] = v0.y; A[r][2] = v0.z; A[r][3] = v0.w;
                A[r][4] = v1.x; A[r][5] = v1.y; A[r][6] = v1.z; A[r][7] = v1.w;
            }
        } else {
            #pragma unroll
            for (int r = 0; r < RH; ++r) {
                const int yr = gy + r;
                const int yy = min(max(yr, 0), IMG_H - 1);
                float rmv = (yr >= 0 && yr < IMG_H) ? 1.f : 0.f;
                const float* rp = xc + (size_t)yy * IMG_W;
                #pragma unroll
                for (int c = 0; c < RW; ++c) {
                    const int xr = gx + c;
                    const int xx = min(max(xr, 0), IMG_W - 1);
                    float m = rmv;
                    if (XM) m *= colm[c];
                    A[r][c] = rp[xx] * m;
                }
            }
        }
    } else {
        #pragma unroll
        for (int r = 0; r < RH; ++r) {
            const float4* rp = (const float4*)(xc + (size_t)(gy + r) * IMG_W + gx);
            float4 v0 = rp[0], v1 = rp[1];
            A[r][0] = v0.x; A[r][1] = v0.y; A[r][2] = v0.z; A[r][3] = v0.w;
            A[r][4] = v1.x; A[r][5] = v1.y; A[r][6] = v1.z; A[r][7] = v1.w;
        }
    }
    #pragma unroll
    for (int r = 0; r < RH; ++r) {
        #pragma unroll
        for (int c = 0; c < RW; ++c) acc[r][c] = A[r][c];
    }

    const int tyu = ty > 0  ? ty - 1 : 0;    // clamped: region-edge garbage OK
    const int tyd = ty < 31 ? ty + 1 : 31;

    #pragma unroll 1
    for (int s = 0; s < NSTEP; ++s) {
        const int buf = s & 1;
        float h0[RW], h3[RW];
        hrow(A[0], h0);
        hrow(A[RH - 1], h3);
        topH4[buf][0][ty][tx] = make_float4(h0[0], h0[1], h0[2], h0[3]);
        topH4[buf][1][ty][tx] = make_float4(h0[4], h0[5], h0[6], h0[7]);
        botH4[buf][0][ty][tx] = make_float4(h3[0], h3[1], h3[2], h3[3]);
        botH4[buf][1][ty][tx] = make_float4(h3[4], h3[5], h3[6], h3[7]);
        __syncthreads();
        float hm1[RW], hbot[RW];
        {
            float4 u0 = botH4[buf][0][tyu][tx], u1 = botH4[buf][1][tyu][tx];
            float4 d0 = topH4[buf][0][tyd][tx], d1 = topH4[buf][1][tyd][tx];
            hm1[0] = u0.x; hm1[1] = u0.y; hm1[2] = u0.z; hm1[3] = u0.w;
            hm1[4] = u1.x; hm1[5] = u1.y; hm1[6] = u1.z; hm1[7] = u1.w;
            hbot[0] = d0.x; hbot[1] = d0.y; hbot[2] = d0.z; hbot[3] = d0.w;
            hbot[4] = d1.x; hbot[5] = d1.y; hbot[6] = d1.z; hbot[7] = d1.w;
        }
        float h1[RW]; hrow(A[1], h1);
        rowop<XM, YM>(hm1, h0, h1, A[0], acc[0], colm, YM ? rowm[0] : 1.f, needR);
        float h2[RW]; hrow(A[2], h2);
        rowop<XM, YM>(h0, h1, h2, A[1], acc[1], colm, YM ? rowm[1] : 1.f, needR);
        rowop<XM, YM>(h1, h2, h3, A[2], acc[2], colm, YM ? rowm[2] : 1.f, needR);
        rowop<XM, YM>(h2, h3, hbot, A[3], acc[3], colm, YM ? rowm[3] : 1.f, needR);
        // no second barrier: next step uses the other LDS buffer; re-writes of
        // THIS buffer happen after the next step's barrier.
    }

    // Epilogue: store central TILE x TILE (region coords [HALO, HALO+TILE)).
    // Rows: chunk rows 4*ty..4*ty+3 lie fully inside [20,108) iff 5<=ty<=26.
    if (XM || YM) {
        #pragma unroll
        for (int r = 0; r < RH; ++r) {
            const int rr = ry + r;
            const int yy = gy0 + rr;
            if (rr >= HALO && rr < HALO + TILE && yy < IMG_H) {
                #pragma unroll
                for (int c = 0; c < RW; ++c) {
                    const int cc = rx + c;
                    const int xx = gx0 + cc;
                    if (cc >= HALO && cc < HALO + TILE && xx < IMG_W)
                        oc[(size_t)yy * IMG_W + xx] = 0.05f * acc[r][c];
                }
            }
        }
    } else {
        if (ty >= 5 && ty <= 26) {
            #pragma unroll
            for (int r = 0; r < RH; ++r) {
                const int yy = gy0 + ry + r;
                float* rowp = oc + (size_t)yy * IMG_W + gx;
                if (tx >= 3 && tx <= 12) {
                    ((float4*)rowp)[0] = make_float4(0.05f * acc[r][0], 0.05f * acc[r][1],
                                                     0.05f * acc[r][2], 0.05f * acc[r][3]);
                    ((float4*)rowp)[1] = make_float4(0.05f * acc[r][4], 0.05f * acc[r][5],
                                                     0.05f * acc[r][6], 0.05f * acc[r][7]);
                } else if (tx == 2) {        // cols 16..23, valid 20..23 -> c=4..7
                    ((float4*)rowp)[1] = make_float4(0.05f * acc[r][4], 0.05f * acc[r][5],
                                                     0.05f * acc[r][6], 0.05f * acc[r][7]);
                } else if (tx == 13) {       // cols 104..111, valid 104..107 -> c=0..3
                    ((float4*)rowp)[0] = make_float4(0.05f * acc[r][0], 0.05f * acc[r][1],
                                                     0.05f * acc[r][2], 0.05f * acc[r][3]);
                }
            }
        }
    }
}

__global__ __launch_bounds__(512, 4)
void blur_outwards_kernel(const float* __restrict__ x, float* __restrict__ out) {
    __shared__ float4 topH4[2][2][32][16];   // 32 KB
    __shared__ float4 botH4[2][2][32][16];   // 32 KB

    const int tid = threadIdx.x;
    const int tx = tid & 15;
    const int ty = tid >> 4;        // 0..31

    const int ch  = blockIdx.z;                       // 0..95
    const int gx0 = (int)blockIdx.x * TILE - HALO;
    const int gy0 = (int)blockIdx.y * TILE - HALO;

    const float* __restrict__ xc = x + (size_t)ch * (IMG_W * IMG_H);
    float* __restrict__ oc = out + (size_t)ch * (IMG_W * IMG_H);

    const bool xe = (gx0 < 0) || (gx0 + REG > IMG_W);
    const bool ye = (gy0 < 0) || (gy0 + REG > IMG_H);
    if (!xe && !ye)      body<false, false>(xc, oc, gx0, gy0, tx, ty, topH4, botH4);
    else if (xe && !ye)  body<true,  false>(xc, oc, gx0, gy0, tx, ty, topH4, botH4);
    else if (!xe && ye)  body<false, true >(xc, oc, gx0, gy0, tx, ty, topH4, botH4);
    else                 body<true,  true >(xc, oc, gx0, gy0, tx, ty, topH4, botH4);
}

extern "C" void kernel_launch(void* const* d_in, const int* in_sizes, int n_in,
                              void* d_out, int out_size, void* d_ws, size_t ws_size,
                              hipStream_t stream) {
    const float* x = (const float*)d_in[0];
    float* out = (float*)d_out;
    dim3 grid((IMG_W + TILE - 1) / TILE,   // 6
              (IMG_H + TILE - 1) / TILE,   // 6
              96);                          // 32 batch * 3 channels
    blur_outwards_kernel<<<grid, 512, 0, stream>>>(x, out);
}